// Round 2
// baseline (635.452 us; speedup 1.0000x reference)
//
#include <hip/hip_runtime.h>
#include <stdint.h>

// ---------------------------------------------------------------------------
// VQ-VAE layer, all-bf16 MFMA pipeline.
// R9 -> R10: R9's all-LDS restructure doubled LDS-port load (reads 41us +
// DMA writes 27us + conflicts 14us = 82us/CU > 66us MFMA floor) -- LDS became
// the wall. Revert to R8's hybrid traffic split (codes [0,64) of each
// 128-chunk via DMA->LDS, codes [64,128) direct global->reg) which halves
// LDS traffic, but fix R8's stall: gbuf ring deepened to 4 slots (3-iter
// prefetch ~465cyc >= 225cyc L2 latency) and the chunk-top drain vmcnt(0)
// replaced by a counted vmcnt(3) that leaves the 3 cross-boundary gbuf
// prefetches in flight (never-drain, AITER-style). DMA[ch+1] issued after
// the wait so it never enters the count. ds ring depth-2 now covers ~310cyc
// (8 MFMA/ks). Wave-private slabs, no barriers in main loop.
// ---------------------------------------------------------------------------

typedef short bf16x8 __attribute__((ext_vector_type(8)));
typedef float f32x4 __attribute__((ext_vector_type(4)));

__device__ __forceinline__ void gl2lds16(const void* g, void* l) {
  __builtin_amdgcn_global_load_lds(
      (const __attribute__((address_space(1))) void*)g,
      (__attribute__((address_space(3))) void*)l, 16, 0, 0);
}

__device__ __forceinline__ float bf2f(unsigned short u) {
  return __uint_as_float(((unsigned)u) << 16);
}
__device__ __forceinline__ unsigned short f2bf(float f) {
  unsigned x = __float_as_uint(f);
  unsigned r = (x + 0x7fffu + ((x >> 16) & 1u)) >> 16;  // RNE
  return (unsigned short)r;
}
__device__ __forceinline__ unsigned long long packScore(float s, int code) {
  unsigned u = __float_as_uint(s);
  u = (u & 0x80000000u) ? ~u : (u | 0x80000000u);  // monotone map f32 -> u32
  return ((unsigned long long)u << 32) | (unsigned)code;
}
__device__ __forceinline__ unsigned long long shflxor_u64(unsigned long long v, int m) {
  union { unsigned long long u; int i[2]; } a;
  a.u = v;
  a.i[0] = __shfl_xor(a.i[0], m);
  a.i[1] = __shfl_xor(a.i[1], m);
  return a.u;
}

// ---------------------------------------------------------------------------
// cast fp32 -> bf16 (vectorized, n4 = count/4)
__global__ __launch_bounds__(256)
void cast_bf16(const float* __restrict__ X, unsigned short* __restrict__ Y, int n4) {
  int i = blockIdx.x * 256 + threadIdx.x;
  if (i < n4) {
    float4 v = ((const float4*)X)[i];
    ushort4 o = make_ushort4(f2bf(v.x), f2bf(v.y), f2bf(v.z), f2bf(v.w));
    ((ushort4*)Y)[i] = o;
  }
}

// transpose 1024x1024 fp32 W[i][j] -> bf16 Wt[j][i]
__global__ __launch_bounds__(256)
void transpose_cast(const float* __restrict__ W, unsigned short* __restrict__ Wt, int D) {
  __shared__ float s[32][33];
  int tx = threadIdx.x & 31, ty = threadIdx.x >> 5;  // 32x8
  int bx = blockIdx.x, by = blockIdx.y;
#pragma unroll
  for (int p = 0; p < 4; p++) {
    int r = by * 32 + ty + p * 8, c = bx * 32 + tx;
    s[ty + p * 8][tx] = W[(size_t)r * D + c];
  }
  __syncthreads();
#pragma unroll
  for (int p = 0; p < 4; p++) {
    int r = bx * 32 + ty + p * 8, c = by * 32 + tx;
    Wt[(size_t)r * D + c] = f2bf(s[tx][ty + p * 8]);
  }
}

// per-code squared norms (fp32), one wave per code row of 256
__global__ __launch_bounds__(256)
void code_norms(const float* __restrict__ cb, float* __restrict__ cn) {
  int row = blockIdx.x * 4 + (threadIdx.x >> 6);
  int lane = threadIdx.x & 63;
  float4 v = ((const float4*)(cb + (size_t)row * 256))[lane];
  float s = v.x * v.x + v.y * v.y + v.z * v.z + v.w * v.w;
#pragma unroll
  for (int off = 32; off > 0; off >>= 1) s += __shfl_down(s, off);
  if (lane == 0) cn[row] = s;
}

// ---------------------------------------------------------------------------
// GEMM: C[M,N] bf16 = relu(A[M,K]bf16 @ Bt[N,K]^T bf16 + bias)
// 128x128 tile, BK=64, DMA staging (global_load_lds w=16) + XOR swizzle.
__global__ __launch_bounds__(256, 2)
void gemm_bias_relu(const unsigned short* __restrict__ A, const unsigned short* __restrict__ Bt,
                    const float* __restrict__ bias, unsigned short* __restrict__ C,
                    int M, int N, int K) {
  __shared__ unsigned short As[128 * 64];
  __shared__ unsigned short Bs[128 * 64];
  const int t = threadIdx.x;
  const int wv = t >> 6, lane = t & 63;
  const int wm = wv >> 1, wn = wv & 1;
  const int quad = lane >> 4, l15 = lane & 15;
  const int row0 = blockIdx.y * 128, col0 = blockIdx.x * 128;
  const int rsub = lane >> 3;            // row within 8-row slab
  const int dchunk = (lane & 7) ^ rsub;  // xor-swizzled data chunk to fetch

  f32x4 acc[4][4];
#pragma unroll
  for (int i = 0; i < 4; i++)
#pragma unroll
    for (int j = 0; j < 4; j++) acc[i][j] = (f32x4){0.f, 0.f, 0.f, 0.f};

  for (int k0 = 0; k0 < K; k0 += 64) {
#pragma unroll
    for (int j = 0; j < 4; j++) {
      int slab = j * 4 + wv;            // 16 slabs of 8 rows (1024 B each)
      int row = slab * 8 + rsub;
      gl2lds16(A + (size_t)(row0 + row) * K + k0 + dchunk * 8, As + slab * 512);
      gl2lds16(Bt + (size_t)(col0 + row) * K + k0 + dchunk * 8, Bs + slab * 512);
    }
    __syncthreads();
#pragma unroll
    for (int kk = 0; kk < 2; kk++) {
      bf16x8 af[4], bfr[4];
#pragma unroll
      for (int mt = 0; mt < 4; mt++) {
        int row = wm * 64 + mt * 16 + l15;
        af[mt] = *(const bf16x8*)(As + row * 64 + (((kk * 4 + quad) ^ (l15 & 7)) * 8));
      }
#pragma unroll
      for (int nt = 0; nt < 4; nt++) {
        int row = wn * 64 + nt * 16 + l15;
        bfr[nt] = *(const bf16x8*)(Bs + row * 64 + (((kk * 4 + quad) ^ (l15 & 7)) * 8));
      }
#pragma unroll
      for (int mt = 0; mt < 4; mt++)
#pragma unroll
        for (int nt = 0; nt < 4; nt++)
          acc[mt][nt] = __builtin_amdgcn_mfma_f32_16x16x32_bf16(af[mt], bfr[nt], acc[mt][nt], 0, 0, 0);
    }
    __syncthreads();
  }
#pragma unroll
  for (int mt = 0; mt < 4; mt++) {
#pragma unroll
    for (int nt = 0; nt < 4; nt++) {
      int col = col0 + wn * 64 + nt * 16 + l15;
      float b = bias[col];
#pragma unroll
      for (int r = 0; r < 4; r++) {
        int row = row0 + wm * 64 + mt * 16 + quad * 4 + r;
        float v = acc[mt][nt][r] + b;
        C[(size_t)row * N + col] = f2bf(v > 0.f ? v : 0.f);
      }
    }
  }
}

// ---------------------------------------------------------------------------
// LayerNorm over rows of 1024 (bf16 in); writes bf16 (obf) or fp32 (of32)
__global__ __launch_bounds__(256)
void ln_kernel(const unsigned short* __restrict__ X, const float* __restrict__ g,
               const float* __restrict__ b, unsigned short* __restrict__ obf,
               float* __restrict__ of32) {
  const int row = blockIdx.x, t = threadIdx.x;
  ushort4 u = ((const ushort4*)(X + (size_t)row * 1024))[t];
  float4 v = make_float4(bf2f(u.x), bf2f(u.y), bf2f(u.z), bf2f(u.w));
  float s = v.x + v.y + v.z + v.w;
  float ss = v.x * v.x + v.y * v.y + v.z * v.z + v.w * v.w;
#pragma unroll
  for (int off = 32; off > 0; off >>= 1) {
    s += __shfl_down(s, off);
    ss += __shfl_down(ss, off);
  }
  __shared__ float rs[4], rss[4];
  const int wave = t >> 6, lane = t & 63;
  if (lane == 0) { rs[wave] = s; rss[wave] = ss; }
  __syncthreads();
  float S = rs[0] + rs[1] + rs[2] + rs[3];
  float SS = rss[0] + rss[1] + rss[2] + rss[3];
  float m = S * (1.0f / 1024.0f);
  float var = SS * (1.0f / 1024.0f) - m * m;
  float rstd = 1.0f / sqrtf(var + 1e-5f);
  float4 gv = ((const float4*)g)[t];
  float4 bv = ((const float4*)b)[t];
  float4 o;
  o.x = (v.x - m) * rstd * gv.x + bv.x;
  o.y = (v.y - m) * rstd * gv.y + bv.y;
  o.z = (v.z - m) * rstd * gv.z + bv.z;
  o.w = (v.w - m) * rstd * gv.w + bv.w;
  if (obf) {
    ushort4 q = make_ushort4(f2bf(o.x), f2bf(o.y), f2bf(o.z), f2bf(o.w));
    ((ushort4*)(obf + (size_t)row * 1024))[t] = q;
  } else {
    ((float4*)(of32 + (size_t)row * 1024))[t] = o;
  }
}

// ---------------------------------------------------------------------------
// VQ distance+argmin: Z[32768,256]bf16 vs Cb[8192,256]bf16.
// Block = 64 Z-rows x ALL 8192 codes (grid 512). Z register-resident zf[4][8].
// Chunk = 128 codes: [0,64) DMA-staged to LDS (dbuf 2x32KB, XOR swizzle,
// WAVE-PRIVATE slabs), [64,128) direct global->reg via 4-slot gbuf ring
// prefetched 3 iterations ahead (~465cyc cover >= 225cyc L2 latency).
// NO barriers in the main loop. Chunk top does a COUNTED s_waitcnt vmcnt(3):
// age order is DMA[ch](8,oldest) < cnorm(2) < gbuf tail prefetch(3,newest),
// so vmcnt(3) retires DMA+cnorm and leaves the gbuf ring in flight.
// DMA[ch+1] is issued strictly AFTER the wait (never enters the count).
__global__ __launch_bounds__(256, 2)
void vq_dist(const unsigned short* __restrict__ Z, const unsigned short* __restrict__ Cb,
             const float* __restrict__ cnorm, unsigned long long* __restrict__ bestg) {
  __shared__ unsigned short Bs[2][64 * 256];  // 2 x 32KB
  __shared__ unsigned long long runmin[64];
  const int t = threadIdx.x;
  const int wv = t >> 6, lane = t & 63;
  const int quad = lane >> 4, l15 = lane & 15;
  const int row0 = blockIdx.x * 64;

  if (t < 64) runmin[t] = ~0ull;

  // Z fragments for this wave: rows mt*16+l15, K-step ks (8 bf16 each)
  bf16x8 zf[4][8];
#pragma unroll
  for (int mt = 0; mt < 4; mt++)
#pragma unroll
    for (int ks = 0; ks < 8; ks++)
      zf[mt][ks] = *(const bf16x8*)(Z + (size_t)(row0 + mt * 16 + l15) * 256 + ks * 32 + quad * 8);

  float msc[4][4];
  int mcd[4][4];
#pragma unroll
  for (int mt = 0; mt < 4; mt++)
#pragma unroll
    for (int r = 0; r < 4; r++) { msc[mt][r] = 3.4e38f; mcd[mt][r] = 0; }

  // LDS staging geometry: chunk ch codes [ch*128, ch*128+64) -> Bs[ch&1],
  // 32 slabs of 1KB (2 codes each). Wave wv stages slabs [8wv,8wv+8) ==
  // exactly slots [16wv,16wv+16) that it reads.
  const int dcode = lane >> 5;  // 0/1 within slab
  const int dgr = lane & 31;    // 16B granule within code row
  const int slot = wv * 16 + l15;
  const int rxor = l15 & 7;

  // direct-global half: codes ch*128 + 64 + slot, dims ks*32 + quad*8
  const unsigned short* gbase = Cb + (size_t)(64 + slot) * 256 + quad * 8;

  // ---- prologue ----
  // stage chunk 0 LDS half into Bs[0]
#pragma unroll
  for (int j = 0; j < 8; j++) {
    int slab = wv * 8 + j;
    int sl = slab * 2 + dcode;
    gl2lds16(Cb + (size_t)sl * 256 + ((dgr ^ (sl & 7)) * 8), &Bs[0][slab * 512]);
  }
  // cnorm for chunk 0
  float cn0c = cnorm[slot];
  float cn1c = cnorm[64 + slot];
  float cn0p = 3.4e38f, cn1p = 3.4e38f;  // sentinel: ch=-1 argmin never wins
  // gbuf ring: prefetch (ch0, ks0..2)
  bf16x8 gbuf[4];
  gbuf[0] = *(const bf16x8*)(gbase + 0 * 32);
  gbuf[1] = *(const bf16x8*)(gbase + 1 * 32);
  gbuf[2] = *(const bf16x8*)(gbase + 2 * 32);

  f32x4 pacc[4][2];
#pragma unroll
  for (int mt = 0; mt < 4; mt++) {
    pacc[mt][0] = (f32x4){0.f, 0.f, 0.f, 0.f};
    pacc[mt][1] = (f32x4){0.f, 0.f, 0.f, 0.f};
  }

  for (int ch = 0; ch < 64; ch++) {
    const int cur = ch & 1;
    // COUNTED wait: retire DMA[ch] (8) + cnorm (2); leave the 3 gbuf
    // prefetches for this chunk's ks0..2 in flight. lgkm/exp no-wait.
    __builtin_amdgcn_s_waitcnt(0x3F73);
    __builtin_amdgcn_sched_barrier(0);

    // issue DMA for chunk ch+1 LDS half (wrap: junk refill, never read)
    {
      const int cb2 = ((ch + 1) & 63) * 128;
#pragma unroll
      for (int j = 0; j < 8; j++) {
        int slab = wv * 8 + j;
        int sl = slab * 2 + dcode;
        gl2lds16(Cb + (size_t)(cb2 + sl) * 256 + ((dgr ^ (sl & 7)) * 8),
                 &Bs[cur ^ 1][slab * 512]);
      }
    }
    // cnorm for chunk ch+1 (used at top of ch+2)
    float cn0n = cnorm[(((ch + 1) & 63) * 128) + slot];
    float cn1n = cnorm[(((ch + 1) & 63) * 128) + 64 + slot];

    // issue first two LDS reads of this chunk early...
    bf16x8 lbuf[3];
    lbuf[0] = *(const bf16x8*)(&Bs[cur][slot * 256 + ((quad ^ rxor) * 8)]);
    lbuf[1] = *(const bf16x8*)(&Bs[cur][slot * 256 + (((4 + quad) ^ rxor) * 8)]);

    // ...and hide their latency under chunk ch-1's deferred argmin VALU.
    // Per-lane visit order ascending (ch asc, p asc) -> strict < keeps
    // lowest index (reference tie-break).
    {
      int code0 = (ch - 1) * 128 + slot;
#pragma unroll
      for (int p = 0; p < 2; p++) {
        float cn = p == 0 ? cn0p : cn1p;
#pragma unroll
        for (int mt = 0; mt < 4; mt++)
#pragma unroll
          for (int r = 0; r < 4; r++) {
            float sc = cn - 2.0f * pacc[mt][p][r];
            if (sc < msc[mt][r]) { msc[mt][r] = sc; mcd[mt][r] = code0 + p * 64; }
          }
      }
    }

#pragma unroll
    for (int ks = 0; ks < 8; ks++) {
      // LDS ring: depth 2 (3 slots)
      if (ks + 2 < 8)
        lbuf[(ks + 2) % 3] =
            *(const bf16x8*)(&Bs[cur][slot * 256 + ((((ks + 2) * 4 + quad) ^ rxor) * 8)]);
      // gbuf ring: issue load for iteration +3 (4 slots); (ch*8)%4==0 so
      // ring index is ks-only. Wrap at the very end loads chunk 0 (unused).
      {
        const int ksn = (ks + 3) & 7;
        const int chn = (ks + 3 > 7) ? ((ch + 1) & 63) : ch;
        gbuf[(ks + 3) & 3] = *(const bf16x8*)(gbase + (size_t)chn * 32768 + ksn * 32);
      }
      bf16x8 lb = lbuf[ks % 3];
      bf16x8 gb = gbuf[ks & 3];
      if (ks == 0) {
        const f32x4 z4 = (f32x4){0.f, 0.f, 0.f, 0.f};
#pragma unroll
        for (int mt = 0; mt < 4; mt++) {
          pacc[mt][0] = __builtin_amdgcn_mfma_f32_16x16x32_bf16(zf[mt][0], lb, z4, 0, 0, 0);
          pacc[mt][1] = __builtin_amdgcn_mfma_f32_16x16x32_bf16(zf[mt][0], gb, z4, 0, 0, 0);
        }
      } else {
#pragma unroll
        for (int mt = 0; mt < 4; mt++) {
          pacc[mt][0] = __builtin_amdgcn_mfma_f32_16x16x32_bf16(zf[mt][ks], lb, pacc[mt][0], 0, 0, 0);
          pacc[mt][1] = __builtin_amdgcn_mfma_f32_16x16x32_bf16(zf[mt][ks], gb, pacc[mt][1], 0, 0, 0);
        }
      }
    }
    cn0p = cn0c; cn1p = cn1c;
    cn0c = cn0n; cn1c = cn1n;
  }
  // final deferred argmin (chunk 63)
  {
    int code0 = 63 * 128 + slot;
#pragma unroll
    for (int p = 0; p < 2; p++) {
      float cn = p == 0 ? cn0p : cn1p;
#pragma unroll
      for (int mt = 0; mt < 4; mt++)
#pragma unroll
        for (int r = 0; r < 4; r++) {
          float sc = cn - 2.0f * pacc[mt][p][r];
          if (sc < msc[mt][r]) { msc[mt][r] = sc; mcd[mt][r] = code0 + p * 64; }
        }
    }
  }

  __syncthreads();  // runmin init visible; all waves done before merge
#pragma unroll
  for (int mt = 0; mt < 4; mt++) {
#pragma unroll
    for (int r = 0; r < 4; r++) {
      unsigned long long bp = packScore(msc[mt][r], mcd[mt][r]);
#pragma unroll
      for (int m = 1; m < 16; m <<= 1) {
        unsigned long long o = shflxor_u64(bp, m);
        bp = o < bp ? o : bp;
      }
      if (l15 == 0) atomicMin(&runmin[mt * 16 + quad * 4 + r], bp);
    }
  }
  __syncthreads();
  if (t < 64) bestg[row0 + t] = runmin[t];  // block owns these rows exclusively
}

// ---------------------------------------------------------------------------
// gather quantized rows (bf16 for decoder), histogram, per-block loss partial
__global__ __launch_bounds__(256)
void vq_gather(const unsigned long long* __restrict__ bestg, const float* __restrict__ cb,
               const unsigned short* __restrict__ zb, unsigned short* __restrict__ qb,
               int* __restrict__ counts, float* __restrict__ lpart) {
  const int wave = threadIdx.x >> 6;
  const int g = blockIdx.x * 4 + wave;
  const int lane = threadIdx.x & 63;
  const int idx = (int)(bestg[g] & 0xFFFFFFFFull);
  float4 c = ((const float4*)(cb + (size_t)idx * 256))[lane];
  ushort4 q = make_ushort4(f2bf(c.x), f2bf(c.y), f2bf(c.z), f2bf(c.w));
  ((ushort4*)(qb + (size_t)g * 256))[lane] = q;
  ushort4 z = ((const ushort4*)(zb + (size_t)g * 256))[lane];
  float dx = c.x - bf2f(z.x), dy = c.y - bf2f(z.y);
  float dz = c.z - bf2f(z.z), dw = c.w - bf2f(z.w);
  float p = dx * dx + dy * dy + dz * dz + dw * dw;
#pragma unroll
  for (int off = 32; off > 0; off >>= 1) p += __shfl_down(p, off);
  __shared__ float sp[4];
  if (lane == 0) {
    sp[wave] = p;
    atomicAdd(&counts[idx], 1);
  }
  __syncthreads();
  if (threadIdx.x == 0) lpart[blockIdx.x] = sp[0] + sp[1] + sp[2] + sp[3];
}

// loss + perplexity scalars
__global__ __launch_bounds__(256)
void finalize(const int* __restrict__ counts, const float* __restrict__ lpart,
              float* __restrict__ out2) {
  const int t = threadIdx.x;
  double h = 0.0, l = 0.0;
  for (int i = t; i < 8192; i += 256) {
    double pr = (double)counts[i] * (1.0 / 32768.0);
    h += pr * log(pr + 1e-10);
    l += (double)lpart[i];
  }
  __shared__ double sh[256], sl[256];
  sh[t] = h;
  sl[t] = l;
  __syncthreads();
  for (int w = 128; w > 0; w >>= 1) {
    if (t < w) { sh[t] += sh[t + w]; sl[t] += sl[t + w]; }
    __syncthreads();
  }
  if (t == 0) {
    out2[0] = (float)(1.25 * sl[0] * (1.0 / 8388608.0));
    out2[1] = (float)exp(-sh[0]);
  }
}

// ---------------------------------------------------------------------------
extern "C" void kernel_launch(void* const* d_in, const int* in_sizes, int n_in,
                              void* d_out, int out_size, void* d_ws, size_t ws_size,
                              hipStream_t stream) {
  const float* x = (const float*)d_in[0];
  const float* We1 = (const float*)d_in[1];
  const float* be1 = (const float*)d_in[2];
  const float* ge1 = (const float*)d_in[3];
  const float* bne1 = (const float*)d_in[4];
  const float* We2 = (const float*)d_in[5];
  const float* be2 = (const float*)d_in[6];
  const float* ge2 = (const float*)d_in[7];
  const float* bne2 = (const float*)d_in[8];
  const float* Wd1 = (const float*)d_in[9];
  const float* bd1 = (const float*)d_in[10];
  const float* gd1 = (const float*)d_in[11];
  const float* bnd1 = (const float*)d_in[12];
  const float* Wd2 = (const float*)d_in[13];
  const float* bd2 = (const float*)d_in[14];
  const float* gd2 = (const float*)d_in[15];
  const float* bnd2 = (const float*)d_in[16];
  const float* codebook = (const float*)d_in[17];
  float* out = (float*)d_out;

  char* w = (char*)d_ws;
  auto alloc = [&](size_t bytes) -> char* {
    char* p = w;
    w += (bytes + 255) & ~(size_t)255;
    return p;
  };
  unsigned short* xb = (unsigned short*)alloc((size_t)8192 * 1024 * 2);
  unsigned short* wt0 = (unsigned short*)alloc((size_t)1024 * 1024 * 2);
  unsigned short* wt1 = (unsigned short*)alloc((size_t)1024 * 1024 * 2);
  unsigned short* wt2 = (unsigned short*)alloc((size_t)1024 * 1024 * 2);
  unsigned short* wt3 = (unsigned short*)alloc((size_t)1024 * 1024 * 2);
  unsigned short* cbb = (unsigned short*)alloc((size_t)8192 * 256 * 2);
  float* cnorm = (float*)alloc((size_t)8192 * 4);
  unsigned short* act = (unsigned short*)alloc((size_t)8192 * 1024 * 2);
  unsigned short* yb = (unsigned short*)alloc((size_t)8192 * 1024 * 2);
  unsigned short* zb = (unsigned short*)alloc((size_t)8192 * 1024 * 2);
  unsigned short* qb = (unsigned short*)alloc((size_t)8192 * 1024 * 2);
  unsigned long long* best = (unsigned long long*)alloc((size_t)32768 * 8);
  int* counts = (int*)alloc((size_t)8192 * 4);
  float* lpart = (float*)alloc((size_t)8192 * 4);

  hipMemsetAsync(counts, 0, (size_t)8192 * 4, stream);

  cast_bf16<<<(2097152 + 255) / 256, 256, 0, stream>>>(x, xb, 2097152);
  dim3 tg(32, 32);
  transpose_cast<<<tg, 256, 0, stream>>>(We1, wt0, 1024);
  transpose_cast<<<tg, 256, 0, stream>>>(We2, wt1, 1024);
  transpose_cast<<<tg, 256, 0, stream>>>(Wd1, wt2, 1024);
  transpose_cast<<<tg, 256, 0, stream>>>(Wd2, wt3, 1024);
  cast_bf16<<<(524288 + 255) / 256, 256, 0, stream>>>(codebook, cbb, 524288);
  code_norms<<<2048, 256, 0, stream>>>(codebook, cnorm);

  dim3 gg(8, 64);
  // encoder
  gemm_bias_relu<<<gg, 256, 0, stream>>>(xb, wt0, be1, act, 8192, 1024, 1024);
  ln_kernel<<<8192, 256, 0, stream>>>(act, ge1, bne1, yb, nullptr);
  gemm_bias_relu<<<gg, 256, 0, stream>>>(yb, wt1, be2, act, 8192, 1024, 1024);
  ln_kernel<<<8192, 256, 0, stream>>>(act, ge2, bne2, zb, nullptr);
  // VQ
  vq_dist<<<512, 256, 0, stream>>>(zb, cbb, cnorm, best);
  vq_gather<<<8192, 256, 0, stream>>>(best, codebook, zb, qb, counts, lpart);
  // decoder
  gemm_bias_relu<<<gg, 256, 0, stream>>>(qb, wt2, bd1, act, 8192, 1024, 1024);
  ln_kernel<<<8192, 256, 0, stream>>>(act, gd1, bnd1, yb, nullptr);
  gemm_bias_relu<<<gg, 256, 0, stream>>>(yb, wt3, bd2, act, 8192, 1024, 1024);
  ln_kernel<<<8192, 256, 0, stream>>>(act, gd2, bnd2, nullptr, out);

  finalize<<<1, 256, 0, stream>>>(counts, lpart, out + 8388608);
}

// Round 3
// 447.687 us; speedup vs baseline: 1.4194x; 1.4194x over previous
//
#include <hip/hip_runtime.h>
#include <stdint.h>

// ---------------------------------------------------------------------------
// VQ-VAE layer, all-bf16 MFMA pipeline.
// R10 -> R11: R10's counted-vmcnt hybrid spilled to scratch (WRITE_SIZE
// 2.3->20.7MB = spill traffic; gbuf[4]+pacc[4][2]+sched_barrier pinning blew
// the 256-reg budget) -> 350us. Revert to R9's all-LDS chunk=64 structure
// (best known, 178us) with register-accounted micro-fixes only:
//  1. all-8 ds_reads issued at chunk top (lbuf[8], static idx): arrivals
//     (~12cy apart) outpace MFMA consumption (~19.4cy) -> no per-ks lgkm
//     stalls; first-read latency hides under the deferred argmin.
//  2. precomputed swizzled ds-read offsets swz[8] (slot folded in): 1 add
//     per read instead of xor/shift/mul chain (~30 VALU/chunk saved).
//  3. cnorm register diet (2 live, 1 in flight).
//  4. s_setprio(1/0) around the pure 32-MFMA block (waves free-run -> role
//     diversity exists; T5 applies).
// No sched_barrier, no counted vmcnt: keep R9's proven per-wave vmcnt(0)
// drain at chunk top (DMA issued a full chunk earlier -> drain ~free).
// ---------------------------------------------------------------------------

typedef short bf16x8 __attribute__((ext_vector_type(8)));
typedef float f32x4 __attribute__((ext_vector_type(4)));

__device__ __forceinline__ void gl2lds16(const void* g, void* l) {
  __builtin_amdgcn_global_load_lds(
      (const __attribute__((address_space(1))) void*)g,
      (__attribute__((address_space(3))) void*)l, 16, 0, 0);
}

__device__ __forceinline__ float bf2f(unsigned short u) {
  return __uint_as_float(((unsigned)u) << 16);
}
__device__ __forceinline__ unsigned short f2bf(float f) {
  unsigned x = __float_as_uint(f);
  unsigned r = (x + 0x7fffu + ((x >> 16) & 1u)) >> 16;  // RNE
  return (unsigned short)r;
}
__device__ __forceinline__ unsigned long long packScore(float s, int code) {
  unsigned u = __float_as_uint(s);
  u = (u & 0x80000000u) ? ~u : (u | 0x80000000u);  // monotone map f32 -> u32
  return ((unsigned long long)u << 32) | (unsigned)code;
}
__device__ __forceinline__ unsigned long long shflxor_u64(unsigned long long v, int m) {
  union { unsigned long long u; int i[2]; } a;
  a.u = v;
  a.i[0] = __shfl_xor(a.i[0], m);
  a.i[1] = __shfl_xor(a.i[1], m);
  return a.u;
}

// ---------------------------------------------------------------------------
// cast fp32 -> bf16 (vectorized, n4 = count/4)
__global__ __launch_bounds__(256)
void cast_bf16(const float* __restrict__ X, unsigned short* __restrict__ Y, int n4) {
  int i = blockIdx.x * 256 + threadIdx.x;
  if (i < n4) {
    float4 v = ((const float4*)X)[i];
    ushort4 o = make_ushort4(f2bf(v.x), f2bf(v.y), f2bf(v.z), f2bf(v.w));
    ((ushort4*)Y)[i] = o;
  }
}

// transpose 1024x1024 fp32 W[i][j] -> bf16 Wt[j][i]
__global__ __launch_bounds__(256)
void transpose_cast(const float* __restrict__ W, unsigned short* __restrict__ Wt, int D) {
  __shared__ float s[32][33];
  int tx = threadIdx.x & 31, ty = threadIdx.x >> 5;  // 32x8
  int bx = blockIdx.x, by = blockIdx.y;
#pragma unroll
  for (int p = 0; p < 4; p++) {
    int r = by * 32 + ty + p * 8, c = bx * 32 + tx;
    s[ty + p * 8][tx] = W[(size_t)r * D + c];
  }
  __syncthreads();
#pragma unroll
  for (int p = 0; p < 4; p++) {
    int r = bx * 32 + ty + p * 8, c = by * 32 + tx;
    Wt[(size_t)r * D + c] = f2bf(s[tx][ty + p * 8]);
  }
}

// per-code squared norms (fp32), one wave per code row of 256
__global__ __launch_bounds__(256)
void code_norms(const float* __restrict__ cb, float* __restrict__ cn) {
  int row = blockIdx.x * 4 + (threadIdx.x >> 6);
  int lane = threadIdx.x & 63;
  float4 v = ((const float4*)(cb + (size_t)row * 256))[lane];
  float s = v.x * v.x + v.y * v.y + v.z * v.z + v.w * v.w;
#pragma unroll
  for (int off = 32; off > 0; off >>= 1) s += __shfl_down(s, off);
  if (lane == 0) cn[row] = s;
}

// ---------------------------------------------------------------------------
// GEMM: C[M,N] bf16 = relu(A[M,K]bf16 @ Bt[N,K]^T bf16 + bias)
// 128x128 tile, BK=64, DMA staging (global_load_lds w=16) + XOR swizzle.
__global__ __launch_bounds__(256, 2)
void gemm_bias_relu(const unsigned short* __restrict__ A, const unsigned short* __restrict__ Bt,
                    const float* __restrict__ bias, unsigned short* __restrict__ C,
                    int M, int N, int K) {
  __shared__ unsigned short As[128 * 64];
  __shared__ unsigned short Bs[128 * 64];
  const int t = threadIdx.x;
  const int wv = t >> 6, lane = t & 63;
  const int wm = wv >> 1, wn = wv & 1;
  const int quad = lane >> 4, l15 = lane & 15;
  const int row0 = blockIdx.y * 128, col0 = blockIdx.x * 128;
  const int rsub = lane >> 3;            // row within 8-row slab
  const int dchunk = (lane & 7) ^ rsub;  // xor-swizzled data chunk to fetch

  f32x4 acc[4][4];
#pragma unroll
  for (int i = 0; i < 4; i++)
#pragma unroll
    for (int j = 0; j < 4; j++) acc[i][j] = (f32x4){0.f, 0.f, 0.f, 0.f};

  for (int k0 = 0; k0 < K; k0 += 64) {
#pragma unroll
    for (int j = 0; j < 4; j++) {
      int slab = j * 4 + wv;            // 16 slabs of 8 rows (1024 B each)
      int row = slab * 8 + rsub;
      gl2lds16(A + (size_t)(row0 + row) * K + k0 + dchunk * 8, As + slab * 512);
      gl2lds16(Bt + (size_t)(col0 + row) * K + k0 + dchunk * 8, Bs + slab * 512);
    }
    __syncthreads();
#pragma unroll
    for (int kk = 0; kk < 2; kk++) {
      bf16x8 af[4], bfr[4];
#pragma unroll
      for (int mt = 0; mt < 4; mt++) {
        int row = wm * 64 + mt * 16 + l15;
        af[mt] = *(const bf16x8*)(As + row * 64 + (((kk * 4 + quad) ^ (l15 & 7)) * 8));
      }
#pragma unroll
      for (int nt = 0; nt < 4; nt++) {
        int row = wn * 64 + nt * 16 + l15;
        bfr[nt] = *(const bf16x8*)(Bs + row * 64 + (((kk * 4 + quad) ^ (l15 & 7)) * 8));
      }
#pragma unroll
      for (int mt = 0; mt < 4; mt++)
#pragma unroll
        for (int nt = 0; nt < 4; nt++)
          acc[mt][nt] = __builtin_amdgcn_mfma_f32_16x16x32_bf16(af[mt], bfr[nt], acc[mt][nt], 0, 0, 0);
    }
    __syncthreads();
  }
#pragma unroll
  for (int mt = 0; mt < 4; mt++) {
#pragma unroll
    for (int nt = 0; nt < 4; nt++) {
      int col = col0 + wn * 64 + nt * 16 + l15;
      float b = bias[col];
#pragma unroll
      for (int r = 0; r < 4; r++) {
        int row = row0 + wm * 64 + mt * 16 + quad * 4 + r;
        float v = acc[mt][nt][r] + b;
        C[(size_t)row * N + col] = f2bf(v > 0.f ? v : 0.f);
      }
    }
  }
}

// ---------------------------------------------------------------------------
// LayerNorm over rows of 1024 (bf16 in); writes bf16 (obf) or fp32 (of32)
__global__ __launch_bounds__(256)
void ln_kernel(const unsigned short* __restrict__ X, const float* __restrict__ g,
               const float* __restrict__ b, unsigned short* __restrict__ obf,
               float* __restrict__ of32) {
  const int row = blockIdx.x, t = threadIdx.x;
  ushort4 u = ((const ushort4*)(X + (size_t)row * 1024))[t];
  float4 v = make_float4(bf2f(u.x), bf2f(u.y), bf2f(u.z), bf2f(u.w));
  float s = v.x + v.y + v.z + v.w;
  float ss = v.x * v.x + v.y * v.y + v.z * v.z + v.w * v.w;
#pragma unroll
  for (int off = 32; off > 0; off >>= 1) {
    s += __shfl_down(s, off);
    ss += __shfl_down(ss, off);
  }
  __shared__ float rs[4], rss[4];
  const int wave = t >> 6, lane = t & 63;
  if (lane == 0) { rs[wave] = s; rss[wave] = ss; }
  __syncthreads();
  float S = rs[0] + rs[1] + rs[2] + rs[3];
  float SS = rss[0] + rss[1] + rss[2] + rss[3];
  float m = S * (1.0f / 1024.0f);
  float var = SS * (1.0f / 1024.0f) - m * m;
  float rstd = 1.0f / sqrtf(var + 1e-5f);
  float4 gv = ((const float4*)g)[t];
  float4 bv = ((const float4*)b)[t];
  float4 o;
  o.x = (v.x - m) * rstd * gv.x + bv.x;
  o.y = (v.y - m) * rstd * gv.y + bv.y;
  o.z = (v.z - m) * rstd * gv.z + bv.z;
  o.w = (v.w - m) * rstd * gv.w + bv.w;
  if (obf) {
    ushort4 q = make_ushort4(f2bf(o.x), f2bf(o.y), f2bf(o.z), f2bf(o.w));
    ((ushort4*)(obf + (size_t)row * 1024))[t] = q;
  } else {
    ((float4*)(of32 + (size_t)row * 1024))[t] = o;
  }
}

// ---------------------------------------------------------------------------
// VQ distance+argmin: Z[32768,256]bf16 vs Cb[8192,256]bf16.
// Block = 64 Z-rows x ALL 8192 codes (grid 512). Z register-resident zf[4][8].
// Chunk = 64 codes, ALL DMA-staged to LDS (dbuf 2x32KB, XOR swizzle,
// WAVE-PRIVATE slabs: wave wv stages slabs [8wv,8wv+8) == slots it reads).
// NO barriers in the main loop; per-wave s_waitcnt vmcnt(0) at chunk top
// guards the wave's own DMA (issued a full chunk earlier -> ~free).
// Per chunk: issue all 8 ds_reads (precomputed swizzled addrs), run the
// deferred argmin of chunk ch-1 under their latency, then a pure 32-MFMA
// block wrapped in s_setprio(1/0).
__global__ __launch_bounds__(256, 2)
void vq_dist(const unsigned short* __restrict__ Z, const unsigned short* __restrict__ Cb,
             const float* __restrict__ cnorm, unsigned long long* __restrict__ bestg) {
  __shared__ unsigned short Bs[2][64 * 256];  // 2 x 32KB
  __shared__ unsigned long long runmin[64];
  const int t = threadIdx.x;
  const int wv = t >> 6, lane = t & 63;
  const int quad = lane >> 4, l15 = lane & 15;
  const int row0 = blockIdx.x * 64;

  if (t < 64) runmin[t] = ~0ull;

  // Z fragments for this wave: rows mt*16+l15, K-step ks (8 bf16 each)
  bf16x8 zf[4][8];
#pragma unroll
  for (int mt = 0; mt < 4; mt++)
#pragma unroll
    for (int ks = 0; ks < 8; ks++)
      zf[mt][ks] = *(const bf16x8*)(Z + (size_t)(row0 + mt * 16 + l15) * 256 + ks * 32 + quad * 8);

  float msc[4][4];
  int mcd[4][4];
#pragma unroll
  for (int mt = 0; mt < 4; mt++)
#pragma unroll
    for (int r = 0; r < 4; r++) { msc[mt][r] = 3.4e38f; mcd[mt][r] = 0; }

  // LDS staging geometry: chunk ch codes [ch*64, ch*64+64) -> Bs[ch&1],
  // 32 slabs of 1KB (2 codes each). Wave wv stages slabs [8wv,8wv+8) ==
  // exactly slots [16wv,16wv+16) that it reads.
  const int dcode = lane >> 5;  // 0/1 within slab
  const int dgr = lane & 31;    // 16B granule within code row
  const int slot = wv * 16 + l15;
  const int rxor = l15 & 7;

  // precomputed swizzled ds-read offsets (ushort units), slot folded in:
  // one VGPR add per ds_read in the loop instead of the full xor/mul chain.
  unsigned swz[8];
#pragma unroll
  for (int ks = 0; ks < 8; ks++)
    swz[ks] = (unsigned)slot * 256 + (unsigned)(((ks * 4 + quad) ^ rxor) * 8);

  // ---- prologue: stage chunk 0 into Bs[0]; cnorm for chunk 0 ----
#pragma unroll
  for (int j = 0; j < 8; j++) {
    int slab = wv * 8 + j;
    int sl = slab * 2 + dcode;
    gl2lds16(Cb + (size_t)sl * 256 + ((dgr ^ (sl & 7)) * 8), &Bs[0][slab * 512]);
  }
  float cn_old = 3.4e38f;       // sentinel: ch=-1 deferred argmin never wins
  float cn_new = cnorm[slot];   // chunk 0's norm for this lane's code

  f32x4 pacc[4];
#pragma unroll
  for (int mt = 0; mt < 4; mt++) pacc[mt] = (f32x4){0.f, 0.f, 0.f, 0.f};

  for (int ch = 0; ch < 128; ch++) {
    const int cur = ch & 1;
    // wait for THIS wave's outstanding vmem (incl. its DMA for chunk ch,
    // issued a full chunk ago, and the cnorm load); lgkm/exp not waited.
    // Waves stay unsynchronized.
    __builtin_amdgcn_s_waitcnt(0x3F70);

    // prefetch DMA for chunk ch+1 (wrap: junk refill, never read)
    {
      const int cb2 = ((ch + 1) & 127) * 64;
#pragma unroll
      for (int j = 0; j < 8; j++) {
        int slab = wv * 8 + j;
        int sl = slab * 2 + dcode;
        gl2lds16(Cb + (size_t)(cb2 + sl) * 256 + ((dgr ^ (sl & 7)) * 8),
                 &Bs[cur ^ 1][slab * 512]);
      }
    }

    // issue ALL 8 ds_reads for this chunk (arrive ~12cy apart, consumed
    // ~19.4cy apart by the MFMA block -> no per-ks stalls)
    const unsigned short* bsc = &Bs[cur][0];
    bf16x8 lbuf[8];
#pragma unroll
    for (int ks = 0; ks < 8; ks++)
      lbuf[ks] = *(const bf16x8*)(bsc + swz[ks]);

    // deferred argmin for chunk ch-1 under the ds latency.
    // Per-lane visit order ascending in ch -> strict < keeps lowest index
    // (reference tie-break).
    {
      int code = (ch - 1) * 64 + slot;
#pragma unroll
      for (int mt = 0; mt < 4; mt++)
#pragma unroll
        for (int r = 0; r < 4; r++) {
          float sc = cn_old - 2.0f * pacc[mt][r];
          if (sc < msc[mt][r]) { msc[mt][r] = sc; mcd[mt][r] = code; }
        }
    }
    cn_old = cn_new;  // now holds chunk ch's norm (consumed next iteration)
    cn_new = cnorm[(((ch + 1) & 127) * 64) + slot];  // chunk ch+1's norm

    // pure MFMA block
    __builtin_amdgcn_s_setprio(1);
#pragma unroll
    for (int ks = 0; ks < 8; ks++) {
      if (ks == 0) {
        const f32x4 z4 = (f32x4){0.f, 0.f, 0.f, 0.f};
#pragma unroll
        for (int mt = 0; mt < 4; mt++)
          pacc[mt] = __builtin_amdgcn_mfma_f32_16x16x32_bf16(zf[mt][0], lbuf[0], z4, 0, 0, 0);
      } else {
#pragma unroll
        for (int mt = 0; mt < 4; mt++)
          pacc[mt] = __builtin_amdgcn_mfma_f32_16x16x32_bf16(zf[mt][ks], lbuf[ks], pacc[mt], 0, 0, 0);
      }
    }
    __builtin_amdgcn_s_setprio(0);
  }
  // final deferred argmin (chunk 127)
  {
    int code = 127 * 64 + slot;
#pragma unroll
    for (int mt = 0; mt < 4; mt++)
#pragma unroll
      for (int r = 0; r < 4; r++) {
        float sc = cn_old - 2.0f * pacc[mt][r];
        if (sc < msc[mt][r]) { msc[mt][r] = sc; mcd[mt][r] = code; }
      }
  }

  __syncthreads();  // runmin init visible; all waves done before merge
#pragma unroll
  for (int mt = 0; mt < 4; mt++) {
#pragma unroll
    for (int r = 0; r < 4; r++) {
      unsigned long long bp = packScore(msc[mt][r], mcd[mt][r]);
#pragma unroll
      for (int m = 1; m < 16; m <<= 1) {
        unsigned long long o = shflxor_u64(bp, m);
        bp = o < bp ? o : bp;
      }
      if (l15 == 0) atomicMin(&runmin[mt * 16 + quad * 4 + r], bp);
    }
  }
  __syncthreads();
  if (t < 64) bestg[row0 + t] = runmin[t];  // block owns these rows exclusively
}

// ---------------------------------------------------------------------------
// gather quantized rows (bf16 for decoder), histogram, per-block loss partial
__global__ __launch_bounds__(256)
void vq_gather(const unsigned long long* __restrict__ bestg, const float* __restrict__ cb,
               const unsigned short* __restrict__ zb, unsigned short* __restrict__ qb,
               int* __restrict__ counts, float* __restrict__ lpart) {
  const int wave = threadIdx.x >> 6;
  const int g = blockIdx.x * 4 + wave;
  const int lane = threadIdx.x & 63;
  const int idx = (int)(bestg[g] & 0xFFFFFFFFull);
  float4 c = ((const float4*)(cb + (size_t)idx * 256))[lane];
  ushort4 q = make_ushort4(f2bf(c.x), f2bf(c.y), f2bf(c.z), f2bf(c.w));
  ((ushort4*)(qb + (size_t)g * 256))[lane] = q;
  ushort4 z = ((const ushort4*)(zb + (size_t)g * 256))[lane];
  float dx = c.x - bf2f(z.x), dy = c.y - bf2f(z.y);
  float dz = c.z - bf2f(z.z), dw = c.w - bf2f(z.w);
  float p = dx * dx + dy * dy + dz * dz + dw * dw;
#pragma unroll
  for (int off = 32; off > 0; off >>= 1) p += __shfl_down(p, off);
  __shared__ float sp[4];
  if (lane == 0) {
    sp[wave] = p;
    atomicAdd(&counts[idx], 1);
  }
  __syncthreads();
  if (threadIdx.x == 0) lpart[blockIdx.x] = sp[0] + sp[1] + sp[2] + sp[3];
}

// loss + perplexity scalars
__global__ __launch_bounds__(256)
void finalize(const int* __restrict__ counts, const float* __restrict__ lpart,
              float* __restrict__ out2) {
  const int t = threadIdx.x;
  double h = 0.0, l = 0.0;
  for (int i = t; i < 8192; i += 256) {
    double pr = (double)counts[i] * (1.0 / 32768.0);
    h += pr * log(pr + 1e-10);
    l += (double)lpart[i];
  }
  __shared__ double sh[256], sl[256];
  sh[t] = h;
  sl[t] = l;
  __syncthreads();
  for (int w = 128; w > 0; w >>= 1) {
    if (t < w) { sh[t] += sh[t + w]; sl[t] += sl[t + w]; }
    __syncthreads();
  }
  if (t == 0) {
    out2[0] = (float)(1.25 * sl[0] * (1.0 / 8388608.0));
    out2[1] = (float)exp(-sh[0]);
  }
}

// ---------------------------------------------------------------------------
extern "C" void kernel_launch(void* const* d_in, const int* in_sizes, int n_in,
                              void* d_out, int out_size, void* d_ws, size_t ws_size,
                              hipStream_t stream) {
  const float* x = (const float*)d_in[0];
  const float* We1 = (const float*)d_in[1];
  const float* be1 = (const float*)d_in[2];
  const float* ge1 = (const float*)d_in[3];
  const float* bne1 = (const float*)d_in[4];
  const float* We2 = (const float*)d_in[5];
  const float* be2 = (const float*)d_in[6];
  const float* ge2 = (const float*)d_in[7];
  const float* bne2 = (const float*)d_in[8];
  const float* Wd1 = (const float*)d_in[9];
  const float* bd1 = (const float*)d_in[10];
  const float* gd1 = (const float*)d_in[11];
  const float* bnd1 = (const float*)d_in[12];
  const float* Wd2 = (const float*)d_in[13];
  const float* bd2 = (const float*)d_in[14];
  const float* gd2 = (const float*)d_in[15];
  const float* bnd2 = (const float*)d_in[16];
  const float* codebook = (const float*)d_in[17];
  float* out = (float*)d_out;

  char* w = (char*)d_ws;
  auto alloc = [&](size_t bytes) -> char* {
    char* p = w;
    w += (bytes + 255) & ~(size_t)255;
    return p;
  };
  unsigned short* xb = (unsigned short*)alloc((size_t)8192 * 1024 * 2);
  unsigned short* wt0 = (unsigned short*)alloc((size_t)1024 * 1024 * 2);
  unsigned short* wt1 = (unsigned short*)alloc((size_t)1024 * 1024 * 2);
  unsigned short* wt2 = (unsigned short*)alloc((size_t)1024 * 1024 * 2);
  unsigned short* wt3 = (unsigned short*)alloc((size_t)1024 * 1024 * 2);
  unsigned short* cbb = (unsigned short*)alloc((size_t)8192 * 256 * 2);
  float* cnorm = (float*)alloc((size_t)8192 * 4);
  unsigned short* act = (unsigned short*)alloc((size_t)8192 * 1024 * 2);
  unsigned short* yb = (unsigned short*)alloc((size_t)8192 * 1024 * 2);
  unsigned short* zb = (unsigned short*)alloc((size_t)8192 * 1024 * 2);
  unsigned short* qb = (unsigned short*)alloc((size_t)8192 * 1024 * 2);
  unsigned long long* best = (unsigned long long*)alloc((size_t)32768 * 8);
  int* counts = (int*)alloc((size_t)8192 * 4);
  float* lpart = (float*)alloc((size_t)8192 * 4);

  hipMemsetAsync(counts, 0, (size_t)8192 * 4, stream);

  cast_bf16<<<(2097152 + 255) / 256, 256, 0, stream>>>(x, xb, 2097152);
  dim3 tg(32, 32);
  transpose_cast<<<tg, 256, 0, stream>>>(We1, wt0, 1024);
  transpose_cast<<<tg, 256, 0, stream>>>(We2, wt1, 1024);
  transpose_cast<<<tg, 256, 0, stream>>>(Wd1, wt2, 1024);
  transpose_cast<<<tg, 256, 0, stream>>>(Wd2, wt3, 1024);
  cast_bf16<<<(524288 + 255) / 256, 256, 0, stream>>>(codebook, cbb, 524288);
  code_norms<<<2048, 256, 0, stream>>>(codebook, cnorm);

  dim3 gg(8, 64);
  // encoder
  gemm_bias_relu<<<gg, 256, 0, stream>>>(xb, wt0, be1, act, 8192, 1024, 1024);
  ln_kernel<<<8192, 256, 0, stream>>>(act, ge1, bne1, yb, nullptr);
  gemm_bias_relu<<<gg, 256, 0, stream>>>(yb, wt1, be2, act, 8192, 1024, 1024);
  ln_kernel<<<8192, 256, 0, stream>>>(act, ge2, bne2, zb, nullptr);
  // VQ
  vq_dist<<<512, 256, 0, stream>>>(zb, cbb, cnorm, best);
  vq_gather<<<8192, 256, 0, stream>>>(best, codebook, zb, qb, counts, lpart);
  // decoder
  gemm_bias_relu<<<gg, 256, 0, stream>>>(qb, wt2, bd1, act, 8192, 1024, 1024);
  ln_kernel<<<8192, 256, 0, stream>>>(act, gd1, bnd1, yb, nullptr);
  gemm_bias_relu<<<gg, 256, 0, stream>>>(yb, wt3, bd2, act, 8192, 1024, 1024);
  ln_kernel<<<8192, 256, 0, stream>>>(act, gd2, bnd2, nullptr, out);

  finalize<<<1, 256, 0, stream>>>(counts, lpart, out + 8388608);
}